// Round 1
// baseline (198.444 us; speedup 1.0000x reference)
//
#include <hip/hip_runtime.h>

#define B_ 16
#define T_ 12
#define N_ 512
#define D_ 128
#define E_ 32

typedef __attribute__((ext_vector_type(8))) unsigned short u16x8;
typedef __attribute__((ext_vector_type(8))) __bf16 bf16x8;
typedef __attribute__((ext_vector_type(4))) float f32x4;

static __device__ __forceinline__ unsigned short f2bf(float f) {
    unsigned u = __float_as_uint(f);
    unsigned r = (u + 0x7fffu + ((u >> 16) & 1u)) >> 16;
    return (unsigned short)r;
}

static __device__ __forceinline__ bf16x8 bc(u16x8 u) {
    return __builtin_bit_cast(bf16x8, u);
}

// ---------------------------------------------------------------------------
// kA1W: blocks [0,6144): qk = emb @ W_qk + b_qk (fp32) and q=softmax_D -> bf16
//       blocks [6144,6272): WvT[d][k] = bf16(Wv[k][d])
// Softmax reductions via 64-lane shuffle butterfly + 2-entry LDS combine
// (2 barriers instead of 14).
// ---------------------------------------------------------------------------
__global__ __launch_bounds__(128) void kA1W(const float* __restrict__ emb,
                                            const float* __restrict__ Wqk,
                                            const float* __restrict__ bqk,
                                            float* __restrict__ qk,
                                            unsigned short* __restrict__ qb,
                                            const float* __restrict__ Wv,
                                            unsigned short* __restrict__ WvT) {
    if (blockIdx.x >= 6144) {
        int i = (blockIdx.x - 6144) * 128 + threadIdx.x;  // 0..16383
        int d = i >> 7, k = i & 127;
        WvT[d * 128 + k] = f2bf(Wv[k * 128 + d]);
        return;
    }
    int tn = blockIdx.x;
    int d  = threadIdx.x;
    __shared__ float es[E_];
    if (d < E_) es[d] = emb[tn * E_ + d];
    __syncthreads();
    float acc = bqk[d];
#pragma unroll
    for (int e = 0; e < E_; ++e) acc = fmaf(es[e], Wqk[e * D_ + d], acc);
    qk[(size_t)tn * D_ + d] = acc;

    int wv = d >> 6, lane = d & 63;
    float mx = acc;
#pragma unroll
    for (int s = 32; s > 0; s >>= 1) mx = fmaxf(mx, __shfl_xor(mx, s));
    __shared__ float wred[2][2];
    if (lane == 0) wred[0][wv] = mx;
    __syncthreads();
    mx = fmaxf(wred[0][0], wred[0][1]);
    float ex = __expf(acc - mx);
    float sum = ex;
#pragma unroll
    for (int s = 32; s > 0; s >>= 1) sum += __shfl_xor(sum, s);
    if (lane == 0) wred[1][wv] = sum;
    __syncthreads();
    sum = wred[1][0] + wred[1][1];
    qb[(size_t)tn * D_ + d] = f2bf(ex / sum);
}

// ---------------------------------------------------------------------------
// kA2n: kN[t,n,d] = softmax over n of qk[t,n,d], kept [n][d], bf16.
// grid (t=12 x dtile=16) = 192 blocks; 256 thr = 32(ni) x 8(dc); 16 n/thread.
// Cross-ni reduction via shuffle butterfly (masks 8/16/32) + 4-wave LDS
// combine — removes the two serial 32-iteration loops on 8 threads.
// ---------------------------------------------------------------------------
__global__ __launch_bounds__(256) void kA2n(const float* __restrict__ qk,
                                            unsigned short* __restrict__ kN) {
    int t = blockIdx.x >> 4;
    int d0 = (blockIdx.x & 15) * 8;
    int tid = threadIdx.x;
    int dc = tid & 7, ni = tid >> 3;  // ni 0..31
    const float* base = qk + (size_t)t * N_ * D_ + d0 + dc;
    float vals[16];
    float mx = -1e30f;
#pragma unroll
    for (int j = 0; j < 16; ++j) {
        vals[j] = base[(size_t)(ni + 32 * j) * D_];
        mx = fmaxf(mx, vals[j]);
    }
#pragma unroll
    for (int s = 8; s < 64; s <<= 1) mx = fmaxf(mx, __shfl_xor(mx, s));
    __shared__ float red[2][4][8];
    int wv = tid >> 6;
    if ((tid & 63) < 8) red[0][wv][dc] = mx;
    __syncthreads();
    mx = fmaxf(fmaxf(red[0][0][dc], red[0][1][dc]),
               fmaxf(red[0][2][dc], red[0][3][dc]));
    float sum = 0.f;
#pragma unroll
    for (int j = 0; j < 16; ++j) {
        vals[j] = __expf(vals[j] - mx);
        sum += vals[j];
    }
#pragma unroll
    for (int s = 8; s < 64; s <<= 1) sum += __shfl_xor(sum, s);
    if ((tid & 63) < 8) red[1][wv][dc] = sum;
    __syncthreads();
    sum = red[1][0][dc] + red[1][1][dc] + red[1][2][dc] + red[1][3][dc];
    float inv = 1.f / sum;
    unsigned short* op = kN + (size_t)t * N_ * D_ + d0 + dc;
#pragma unroll
    for (int j = 0; j < 16; ++j)
        op[(size_t)(ni + 32 * j) * D_] = f2bf(vals[j] * inv);
}

// ---------------------------------------------------------------------------
// kF: fused independent mid-stage. 256 thr. NO LDS, NO BARRIERS:
//  all MFMA fragments are K-contiguous in global memory, and every tile is
//  L2/L3-resident, so fragments load straight from global (16B/lane).
//  blocks [0,192):    A3m: sc[t,n,m] = qb @ kN^T (bf16 MFMA, 128x128 tile)
//  blocks [192,960):  Bm:  vT[bt][d][m] = WvT @ value^T + bv (bf16 MFMA)
//  blocks [960,1472): M:   pack mask into bitmask words
// ---------------------------------------------------------------------------
__global__ __launch_bounds__(256) void kF(const unsigned short* __restrict__ qb,
                                          const unsigned short* __restrict__ kN,
                                          unsigned short* __restrict__ sc,
                                          const float* __restrict__ value,
                                          const unsigned short* __restrict__ WvT,
                                          const float* __restrict__ bv,
                                          unsigned short* __restrict__ vT,
                                          const int* __restrict__ mask,
                                          unsigned* __restrict__ mb) {
    int bid = blockIdx.x;
    int tid = threadIdx.x;

    if (bid >= 960) {  // ---- kM ----
        int o = (bid - 960) * 256 + tid;  // 0..131071
        const int* mp = mask + (size_t)o * 32;
        unsigned bits = 0;
#pragma unroll
        for (int j = 0; j < 32; j += 4) {
            int4 m4 = *(const int4*)&mp[j];
            bits |= (m4.x ? 1u : 0u) << j;
            bits |= (m4.y ? 1u : 0u) << (j + 1);
            bits |= (m4.z ? 1u : 0u) << (j + 2);
            bits |= (m4.w ? 1u : 0u) << (j + 3);
        }
        mb[o] = bits;
        return;
    }

    int wave = tid >> 6, lane = tid & 63;
    int q = lane >> 4, lr = lane & 15;
    int rbase = (wave & 1) * 64, cbase = (wave >> 1) * 64;

    f32x4 acc[4][4];
#pragma unroll
    for (int i = 0; i < 4; ++i)
#pragma unroll
        for (int j = 0; j < 4; ++j) acc[i][j] = (f32x4){0.f, 0.f, 0.f, 0.f};

    if (bid < 192) {  // ---- kA3m ----
        int mt = bid & 3, nt = (bid >> 2) & 3, t = bid >> 4;
        int n0 = nt * 128, m0 = mt * 128;
        const unsigned short* qp = qb + (size_t)t * N_ * D_ + (size_t)n0 * D_;
        const unsigned short* kp = kN + (size_t)t * N_ * D_ + (size_t)m0 * D_;
        const unsigned short* ar[4];
        const unsigned short* br[4];
#pragma unroll
        for (int i = 0; i < 4; ++i) ar[i] = qp + (size_t)(rbase + 16 * i + lr) * D_ + q * 8;
#pragma unroll
        for (int j = 0; j < 4; ++j) br[j] = kp + (size_t)(cbase + 16 * j + lr) * D_ + q * 8;
#pragma unroll
        for (int kk = 0; kk < 4; ++kk) {  // K = 128 in 4 chunks of 32
            bf16x8 a[4], b[4];
#pragma unroll
            for (int i = 0; i < 4; ++i) a[i] = bc(*(const u16x8*)(ar[i] + kk * 32));
#pragma unroll
            for (int j = 0; j < 4; ++j) b[j] = bc(*(const u16x8*)(br[j] + kk * 32));
#pragma unroll
            for (int i = 0; i < 4; ++i)
#pragma unroll
                for (int j = 0; j < 4; ++j)
                    acc[i][j] = __builtin_amdgcn_mfma_f32_16x16x32_bf16(
                        a[i], b[j], acc[i][j], 0, 0, 0);
        }
        unsigned short* sp = sc + (size_t)t * N_ * N_;
#pragma unroll
        for (int i = 0; i < 4; ++i)
#pragma unroll
            for (int j = 0; j < 4; ++j) {
                int row0 = n0 + rbase + 16 * i + q * 4;
                int col = m0 + cbase + 16 * j + lr;
#pragma unroll
                for (int e = 0; e < 4; ++e)
                    sp[(size_t)(row0 + e) * N_ + col] = f2bf(acc[i][j][e]);
            }
        return;
    }

    // ---- kBm ----
    {
        int idx = bid - 192;
        int mt = idx & 3, bt = idx >> 2;
        int m0 = mt * 128;
        const float* vp = value + ((size_t)bt * N_ + m0) * D_;
        const unsigned short* wr_[4];
        const float* vr_[4];
#pragma unroll
        for (int i = 0; i < 4; ++i) wr_[i] = WvT + (rbase + 16 * i + lr) * 128 + q * 8;
#pragma unroll
        for (int j = 0; j < 4; ++j) vr_[j] = vp + (size_t)(cbase + 16 * j + lr) * D_ + q * 8;
#pragma unroll
        for (int kk = 0; kk < 4; ++kk) {  // K = 128 in 4 chunks of 32
            bf16x8 a[4], b[4];
#pragma unroll
            for (int i = 0; i < 4; ++i) a[i] = bc(*(const u16x8*)(wr_[i] + kk * 32));
#pragma unroll
            for (int j = 0; j < 4; ++j) {
                float4 f0 = *(const float4*)(vr_[j] + kk * 32);
                float4 f1 = *(const float4*)(vr_[j] + kk * 32 + 4);
                u16x8 o;
                o[0] = f2bf(f0.x); o[1] = f2bf(f0.y); o[2] = f2bf(f0.z); o[3] = f2bf(f0.w);
                o[4] = f2bf(f1.x); o[5] = f2bf(f1.y); o[6] = f2bf(f1.z); o[7] = f2bf(f1.w);
                b[j] = bc(o);
            }
#pragma unroll
            for (int i = 0; i < 4; ++i)
#pragma unroll
                for (int j = 0; j < 4; ++j)
                    acc[i][j] = __builtin_amdgcn_mfma_f32_16x16x32_bf16(
                        a[i], b[j], acc[i][j], 0, 0, 0);
        }
        unsigned short* op = vT + (size_t)bt * N_ * D_;
#pragma unroll
        for (int i = 0; i < 4; ++i) {
            int row0 = rbase + 16 * i + q * 4;
#pragma unroll
            for (int j = 0; j < 4; ++j) {
                int col = m0 + cbase + 16 * j + lr;
#pragma unroll
                for (int e = 0; e < 4; ++e)
                    op[(size_t)(row0 + e) * N_ + col] = f2bf(acc[i][j][e] + bv[row0 + e]);
            }
        }
    }
}

// ---------------------------------------------------------------------------
// kC: out[b,t,n,d] = sum_m (mask ? score0 : -1e9) * v[b,t,m,d]  via bf16 MFMA
// tile 128(n) x 128(d), K=512 in 16 chunks of 32. NO LDS, NO BARRIERS:
// sc/vT fragments are K(m)-contiguous in global and L2/L3-resident; the mask
// is applied per A-fragment via an 8-wide cndmask from the packed bit words.
// grid (4, T, B) = 768 blocks = 3 blocks/CU, 256 thr = 4 waves.
// ---------------------------------------------------------------------------
__global__ __launch_bounds__(256) void kC(const unsigned short* __restrict__ sc,
                                          const unsigned* __restrict__ mb,
                                          const unsigned short* __restrict__ vT,
                                          float* __restrict__ out) {
    int n0 = blockIdx.x * 128;
    int t = blockIdx.y, b = blockIdx.z;
    int tid = threadIdx.x;
    int wave = tid >> 6, lane = tid & 63;
    int q = lane >> 4, lr = lane & 15;
    int rbase = (wave & 1) * 64, cbase = (wave >> 1) * 64;

    const unsigned short* scp = sc + (size_t)t * N_ * N_ + (size_t)n0 * N_;
    const unsigned short* vtp = vT + ((size_t)(b * T_ + t)) * N_ * D_;  // [d][m]
    const unsigned* mbp = mb + ((size_t)b * N_ + n0) * 16;

    const unsigned short NEG = 0xCE6E;  // bf16(-1e9)

    f32x4 acc[4][4];
#pragma unroll
    for (int i = 0; i < 4; ++i)
#pragma unroll
        for (int j = 0; j < 4; ++j) acc[i][j] = (f32x4){0.f, 0.f, 0.f, 0.f};

    const unsigned short* ar[4];
    const unsigned* mr[4];
    const unsigned short* br[4];
#pragma unroll
    for (int i = 0; i < 4; ++i) {
        int r = rbase + 16 * i + lr;
        ar[i] = scp + (size_t)r * N_ + q * 8;
        mr[i] = mbp + r * 16;
    }
#pragma unroll
    for (int j = 0; j < 4; ++j) br[j] = vtp + (size_t)(cbase + 16 * j + lr) * N_ + q * 8;

#pragma unroll 4
    for (int kc = 0; kc < 16; ++kc) {  // K = 512 in 16 chunks of 32
        bf16x8 a[4], bb[4];
#pragma unroll
        for (int i = 0; i < 4; ++i) {
            u16x8 s = *(const u16x8*)(ar[i] + kc * 32);
            unsigned bits = mr[i][kc] >> (q * 8);
            u16x8 o;
#pragma unroll
            for (int e = 0; e < 8; ++e) o[e] = ((bits >> e) & 1u) ? s[e] : NEG;
            a[i] = bc(o);
        }
#pragma unroll
        for (int j = 0; j < 4; ++j) bb[j] = bc(*(const u16x8*)(br[j] + kc * 32));
#pragma unroll
        for (int i = 0; i < 4; ++i)
#pragma unroll
            for (int j = 0; j < 4; ++j)
                acc[i][j] = __builtin_amdgcn_mfma_f32_16x16x32_bf16(
                    a[i], bb[j], acc[i][j], 0, 0, 0);
    }

    float* ob = out + ((size_t)(b * T_ + t)) * N_ * D_;
#pragma unroll
    for (int i = 0; i < 4; ++i) {
#pragma unroll
        for (int j = 0; j < 4; ++j) {
            int row0 = n0 + rbase + 16 * i + q * 4;
            int col = cbase + 16 * j + lr;
#pragma unroll
            for (int e = 0; e < 4; ++e)
                ob[(size_t)(row0 + e) * D_ + col] = acc[i][j][e];
        }
    }
}

// ---------------------------------------------------------------------------
extern "C" void kernel_launch(void* const* d_in, const int* in_sizes, int n_in,
                              void* d_out, int out_size, void* d_ws, size_t ws_size,
                              hipStream_t stream) {
    const float* value = (const float*)d_in[0];
    const float* emb   = (const float*)d_in[1];
    const int*   mask  = (const int*)d_in[2];
    const float* Wqk   = (const float*)d_in[3];
    const float* bqk   = (const float*)d_in[4];
    const float* Wv    = (const float*)d_in[5];
    const float* bvv   = (const float*)d_in[6];
    float* out = (float*)d_out;

    float* ws = (float*)d_ws;
    float*          qkf  = ws;                                // 786432 f
    unsigned short* qb   = (unsigned short*)(ws + 786432);    // 786432 u16
    unsigned short* kNb  = (unsigned short*)(ws + 1179648);   // 786432 u16
    unsigned short* scb  = (unsigned short*)(ws + 1572864);   // 3145728 u16
    unsigned short* vtb  = (unsigned short*)(ws + 3145728);   // 12582912 u16
    unsigned short* WvTb = (unsigned short*)(ws + 9437184);   // 16384 u16
    unsigned*       mbp  = (unsigned*)(ws + 9445376);         // 131072 u32

    kA1W<<<6272, 128, 0, stream>>>(emb, Wqk, bqk, qkf, qb, Wv, WvTb);
    kA2n<<<192, 256, 0, stream>>>(qkf, kNb);
    kF<<<1472, 256, 0, stream>>>(qb, kNb, scb, value, WvTb, bvv, vtb, mask, mbp);
    kC<<<dim3(4, T_, B_), 256, 0, stream>>>(scb, mbp, vtb, out);
}

// Round 2
// 161.789 us; speedup vs baseline: 1.2266x; 1.2266x over previous
//
#include <hip/hip_runtime.h>

#define B_ 16
#define T_ 12
#define N_ 512
#define D_ 128
#define E_ 32

typedef __attribute__((ext_vector_type(8))) unsigned short u16x8;
typedef __attribute__((ext_vector_type(8))) __bf16 bf16x8;
typedef __attribute__((ext_vector_type(4))) float f32x4;

static __device__ __forceinline__ unsigned short f2bf(float f) {
    unsigned u = __float_as_uint(f);
    unsigned r = (u + 0x7fffu + ((u >> 16) & 1u)) >> 16;
    return (unsigned short)r;
}

// ---------------------------------------------------------------------------
// kA1W: blocks [0,6144): qk = emb @ W_qk + b_qk (fp32) and q=softmax_D -> bf16
//       blocks [6144,6272): WvT[d][k] = bf16(Wv[k][d])
// ---------------------------------------------------------------------------
__global__ __launch_bounds__(128) void kA1W(const float* __restrict__ emb,
                                            const float* __restrict__ Wqk,
                                            const float* __restrict__ bqk,
                                            float* __restrict__ qk,
                                            unsigned short* __restrict__ qb,
                                            const float* __restrict__ Wv,
                                            unsigned short* __restrict__ WvT) {
    if (blockIdx.x >= 6144) {
        int i = (blockIdx.x - 6144) * 128 + threadIdx.x;  // 0..16383
        int d = i >> 7, k = i & 127;
        WvT[d * 128 + k] = f2bf(Wv[k * 128 + d]);
        return;
    }
    int tn = blockIdx.x;
    int d  = threadIdx.x;
    __shared__ float es[E_];
    if (d < E_) es[d] = emb[tn * E_ + d];
    __syncthreads();
    float acc = bqk[d];
#pragma unroll
    for (int e = 0; e < E_; ++e) acc = fmaf(es[e], Wqk[e * D_ + d], acc);
    qk[(size_t)tn * D_ + d] = acc;

    int wv = d >> 6, lane = d & 63;
    float mx = acc;
#pragma unroll
    for (int s = 32; s > 0; s >>= 1) mx = fmaxf(mx, __shfl_xor(mx, s));
    __shared__ float wred[2][2];
    if (lane == 0) wred[0][wv] = mx;
    __syncthreads();
    mx = fmaxf(wred[0][0], wred[0][1]);
    float ex = __expf(acc - mx);
    float sum = ex;
#pragma unroll
    for (int s = 32; s > 0; s >>= 1) sum += __shfl_xor(sum, s);
    if (lane == 0) wred[1][wv] = sum;
    __syncthreads();
    sum = wred[1][0] + wred[1][1];
    qb[(size_t)tn * D_ + d] = f2bf(ex / sum);
}

// ---------------------------------------------------------------------------
// kA2n: kN[t,n,d] = softmax over n of qk[t,n,d], kept [n][d], bf16.
// ---------------------------------------------------------------------------
__global__ __launch_bounds__(256) void kA2n(const float* __restrict__ qk,
                                            unsigned short* __restrict__ kN) {
    int t = blockIdx.x >> 4;
    int d0 = (blockIdx.x & 15) * 8;
    int tid = threadIdx.x;
    int dc = tid & 7, ni = tid >> 3;  // ni 0..31
    const float* base = qk + (size_t)t * N_ * D_ + d0 + dc;
    float vals[16];
    float mx = -1e30f;
#pragma unroll
    for (int j = 0; j < 16; ++j) {
        vals[j] = base[(size_t)(ni + 32 * j) * D_];
        mx = fmaxf(mx, vals[j]);
    }
#pragma unroll
    for (int s = 8; s < 64; s <<= 1) mx = fmaxf(mx, __shfl_xor(mx, s));
    __shared__ float red[2][4][8];
    int wv = tid >> 6;
    if ((tid & 63) < 8) red[0][wv][dc] = mx;
    __syncthreads();
    mx = fmaxf(fmaxf(red[0][0][dc], red[0][1][dc]),
               fmaxf(red[0][2][dc], red[0][3][dc]));
    float sum = 0.f;
#pragma unroll
    for (int j = 0; j < 16; ++j) {
        vals[j] = __expf(vals[j] - mx);
        sum += vals[j];
    }
#pragma unroll
    for (int s = 8; s < 64; s <<= 1) sum += __shfl_xor(sum, s);
    if ((tid & 63) < 8) red[1][wv][dc] = sum;
    __syncthreads();
    sum = red[1][0][dc] + red[1][1][dc] + red[1][2][dc] + red[1][3][dc];
    float inv = 1.f / sum;
    unsigned short* op = kN + (size_t)t * N_ * D_ + d0 + dc;
#pragma unroll
    for (int j = 0; j < 16; ++j)
        op[(size_t)(ni + 32 * j) * D_] = f2bf(vals[j] * inv);
}

// ---------------------------------------------------------------------------
// kF: fused independent mid-stage (round-0 LDS-staged version, reverted).
//  blocks [0,192):    A3m: sc[t,n,m] = qb @ kN^T (bf16 MFMA, 128x128 tile)
//  blocks [192,960):  Bm:  vT[bt][d][m] = WvT @ value^T + bv (bf16 MFMA)
//  blocks [960,1472): M:   pack mask into bitmask words
// ---------------------------------------------------------------------------
__global__ __launch_bounds__(256) void kF(const unsigned short* __restrict__ qb,
                                          const unsigned short* __restrict__ kN,
                                          unsigned short* __restrict__ sc,
                                          const float* __restrict__ value,
                                          const unsigned short* __restrict__ WvT,
                                          const float* __restrict__ bv,
                                          unsigned short* __restrict__ vT,
                                          const int* __restrict__ mask,
                                          unsigned* __restrict__ mb) {
    __shared__ unsigned short shl[2][128 * 72];
    int bid = blockIdx.x;
    int tid = threadIdx.x;

    if (bid >= 960) {  // ---- kM ----
        int o = (bid - 960) * 256 + tid;  // 0..131071
        const int* mp = mask + (size_t)o * 32;
        unsigned bits = 0;
#pragma unroll
        for (int j = 0; j < 32; j += 4) {
            int4 m4 = *(const int4*)&mp[j];
            bits |= (m4.x ? 1u : 0u) << j;
            bits |= (m4.y ? 1u : 0u) << (j + 1);
            bits |= (m4.z ? 1u : 0u) << (j + 2);
            bits |= (m4.w ? 1u : 0u) << (j + 3);
        }
        mb[o] = bits;
        return;
    }

    int wave = tid >> 6, lane = tid & 63;
    int q = lane >> 4, lr = lane & 15;
    int rbase = (wave & 1) * 64, cbase = (wave >> 1) * 64;

    f32x4 acc[4][4];
#pragma unroll
    for (int i = 0; i < 4; ++i)
#pragma unroll
        for (int j = 0; j < 4; ++j) acc[i][j] = (f32x4){0.f, 0.f, 0.f, 0.f};

    if (bid < 192) {  // ---- kA3m ----
        int mt = bid & 3, nt = (bid >> 2) & 3, t = bid >> 4;
        int n0 = nt * 128, m0 = mt * 128;
        unsigned short* Qs = shl[0];
        unsigned short* Ks = shl[1];
        const unsigned short* qp = qb + (size_t)t * N_ * D_ + (size_t)n0 * D_;
        const unsigned short* kp = kN + (size_t)t * N_ * D_ + (size_t)m0 * D_;

        for (int c = 0; c < 2; ++c) {
            int k0 = c * 64;
            __syncthreads();
#pragma unroll
            for (int i = 0; i < 4; ++i) {
                int lin = tid + i * 256;
                int r = lin >> 3, seg = lin & 7;
                *(u16x8*)&Qs[r * 72 + seg * 8] =
                    *(const u16x8*)&qp[(size_t)r * D_ + k0 + seg * 8];
                *(u16x8*)&Ks[r * 72 + seg * 8] =
                    *(const u16x8*)&kp[(size_t)r * D_ + k0 + seg * 8];
            }
            __syncthreads();
#pragma unroll
            for (int kk = 0; kk < 2; ++kk) {
                bf16x8 a[4], b[4];
#pragma unroll
                for (int i = 0; i < 4; ++i)
                    a[i] = *(const bf16x8*)&Qs[(rbase + 16 * i + lr) * 72 + kk * 32 + q * 8];
#pragma unroll
                for (int j = 0; j < 4; ++j)
                    b[j] = *(const bf16x8*)&Ks[(cbase + 16 * j + lr) * 72 + kk * 32 + q * 8];
#pragma unroll
                for (int i = 0; i < 4; ++i)
#pragma unroll
                    for (int j = 0; j < 4; ++j)
                        acc[i][j] = __builtin_amdgcn_mfma_f32_16x16x32_bf16(
                            a[i], b[j], acc[i][j], 0, 0, 0);
            }
        }
        unsigned short* sp = sc + (size_t)t * N_ * N_;
#pragma unroll
        for (int i = 0; i < 4; ++i)
#pragma unroll
            for (int j = 0; j < 4; ++j) {
                int row0 = n0 + rbase + 16 * i + q * 4;
                int col = m0 + cbase + 16 * j + lr;
#pragma unroll
                for (int e = 0; e < 4; ++e)
                    sp[(size_t)(row0 + e) * N_ + col] = f2bf(acc[i][j][e]);
            }
        return;
    }

    // ---- kBm ----
    {
        int idx = bid - 192;
        int mt = idx & 3, bt = idx >> 2;
        int m0 = mt * 128;
        unsigned short* Ws = shl[0];
        unsigned short* Vs = shl[1];
        const float* vp = value + ((size_t)bt * N_ + m0) * D_;

        for (int c = 0; c < 2; ++c) {
            int k0 = c * 64;
            __syncthreads();
#pragma unroll
            for (int i = 0; i < 4; ++i) {
                int lin = tid + i * 256;
                int r = lin >> 3, seg = lin & 7;
                *(u16x8*)&Ws[r * 72 + seg * 8] =
                    *(const u16x8*)&WvT[r * 128 + k0 + seg * 8];
            }
#pragma unroll
            for (int i = 0; i < 8; ++i) {
                int lin = tid + i * 256;
                int r = lin >> 4, c4 = lin & 15;
                float4 f = *(const float4*)&vp[(size_t)r * D_ + k0 + c4 * 4];
                ushort4 o;
                o.x = f2bf(f.x); o.y = f2bf(f.y); o.z = f2bf(f.z); o.w = f2bf(f.w);
                *(ushort4*)&Vs[r * 72 + c4 * 4] = o;
            }
            __syncthreads();
#pragma unroll
            for (int kk = 0; kk < 2; ++kk) {
                bf16x8 a[4], b[4];
#pragma unroll
                for (int i = 0; i < 4; ++i)
                    a[i] = *(const bf16x8*)&Ws[(rbase + 16 * i + lr) * 72 + kk * 32 + q * 8];
#pragma unroll
                for (int j = 0; j < 4; ++j)
                    b[j] = *(const bf16x8*)&Vs[(cbase + 16 * j + lr) * 72 + kk * 32 + q * 8];
#pragma unroll
                for (int i = 0; i < 4; ++i)
#pragma unroll
                    for (int j = 0; j < 4; ++j)
                        acc[i][j] = __builtin_amdgcn_mfma_f32_16x16x32_bf16(
                            a[i], b[j], acc[i][j], 0, 0, 0);
            }
        }
        unsigned short* op = vT + (size_t)bt * N_ * D_;
#pragma unroll
        for (int i = 0; i < 4; ++i) {
            int row0 = rbase + 16 * i + q * 4;
#pragma unroll
            for (int j = 0; j < 4; ++j) {
                int col = m0 + cbase + 16 * j + lr;
#pragma unroll
                for (int e = 0; e < 4; ++e)
                    op[(size_t)(row0 + e) * N_ + col] = f2bf(acc[i][j][e] + bv[row0 + e]);
            }
        }
    }
}

// ---------------------------------------------------------------------------
// kC: out[b,t,n,d] = sum_m (mask ? score0 : -1e9) * v[b,t,m,d]  via bf16 MFMA
// 128(n) x 128(d) tile, K=512 in 8 chunks of 64.
//  - S: reg-staged (mask fused) -> XOR-swizzled ds_write, single 16 KB buffer
//  - V: global_load_lds width-16 direct to LDS, double-buffered 2x16 KB;
//       swizzled layout via pre-swizzled per-lane GLOBAL source address
//  - raw s_barrier + manual lgkmcnt(0): next chunk's 9 global ops stay in
//    flight across the barrier (drained at next sreg use, under the MFMAs)
// LDS 48 KB -> 3 blocks/CU. grid (4,T,B)=768 blocks, 256 thr.
// ---------------------------------------------------------------------------
__global__ __launch_bounds__(256, 3) void kC(const unsigned short* __restrict__ sc,
                                             const unsigned* __restrict__ mb,
                                             const unsigned short* __restrict__ vT,
                                             float* __restrict__ out) {
    int n0 = blockIdx.x * 128;
    int t = blockIdx.y, b = blockIdx.z;
    int tid = threadIdx.x;
    int wave = tid >> 6, lane = tid & 63;
    int q = lane >> 4, lr = lane & 15;
    int rbase = (wave & 1) * 64, cbase = (wave >> 1) * 64;

    __shared__ unsigned short Sb[128 * 64];
    __shared__ unsigned short Vb[2][128 * 64];

    const unsigned short* scp = sc + (size_t)t * N_ * N_ + (size_t)n0 * N_;
    const unsigned short* vtp = vT + ((size_t)(b * T_ + t)) * N_ * D_;  // [d][m]
    const unsigned* mbp = mb + ((size_t)b * N_ + n0) * 16;
    const unsigned short NEG = 0xCE6E;  // bf16(-1e9)

    f32x4 acc[4][4];
#pragma unroll
    for (int i = 0; i < 4; ++i)
#pragma unroll
        for (int j = 0; j < 4; ++j) acc[i][j] = (f32x4){0.f, 0.f, 0.f, 0.f};

    // ---- S staging assignment: row sr = tid>>1, m-half sh2 = tid&1 ----
    int sr = tid >> 1, sh2 = tid & 1;
    const unsigned short* sg = scp + (size_t)sr * N_ + sh2 * 32;
    const unsigned* mwp = mbp + sr * 16 + sh2;
    int swz_r = (sr & 7) << 4;  // byte XOR for row sr
    char* Sw[4];
#pragma unroll
    for (int p = 0; p < 4; ++p)
        Sw[p] = (char*)Sb + sr * 128 + ((sh2 * 64 + p * 16) ^ swz_r);

    // ---- V gload_lds geometry ----
    int l3 = lane >> 3, l7 = lane & 7;
    int vin = (l7 * 16) ^ (l3 << 4);  // pre-swizzled source inner byte
    const char* vbase = (const char*)vtp;

    // ---- prologue: chunk 0 in flight ----
#pragma unroll
    for (int it = 0; it < 4; ++it) {
        int row = (it * 4 + wave) * 8 + l3;
        const char* src = vbase + (size_t)row * 1024 + vin;
        char* dst = (char*)&Vb[0][0] + ((it * 4 + wave) * 64 + lane) * 16;
        __builtin_amdgcn_global_load_lds(
            (const __attribute__((address_space(1))) unsigned*)src,
            (__attribute__((address_space(3))) unsigned*)dst, 16, 0, 0);
    }
    u16x8 sreg[4];
    unsigned mw;
#pragma unroll
    for (int p = 0; p < 4; ++p) sreg[p] = *(const u16x8*)(sg + p * 8);
    mw = mwp[0];

    for (int kc = 0; kc < 8; ++kc) {
        int cur = kc & 1;
        // 1. masked merge + swizzled ds_write of S (auto-drains chunk-kc loads)
#pragma unroll
        for (int p = 0; p < 4; ++p) {
            unsigned bits = mw >> (p * 8);
            u16x8 o;
#pragma unroll
            for (int j = 0; j < 8; ++j)
                o[j] = ((bits >> j) & 1u) ? sreg[p][j] : NEG;
            *(u16x8*)Sw[p] = o;
        }
        // 2. prefetch chunk kc+1 (stays in flight across the barrier)
        if (kc < 7) {
            int off = (kc + 1) * 128;  // byte offset along m
#pragma unroll
            for (int it = 0; it < 4; ++it) {
                int row = (it * 4 + wave) * 8 + l3;
                const char* src = vbase + (size_t)row * 1024 + off + vin;
                char* dst = (char*)&Vb[cur ^ 1][0] + ((it * 4 + wave) * 64 + lane) * 16;
                __builtin_amdgcn_global_load_lds(
                    (const __attribute__((address_space(1))) unsigned*)src,
                    (__attribute__((address_space(3))) unsigned*)dst, 16, 0, 0);
            }
            int eoff = (kc + 1) * 64;
#pragma unroll
            for (int p = 0; p < 4; ++p) sreg[p] = *(const u16x8*)(sg + eoff + p * 8);
            mw = mwp[(kc + 1) * 2];
        }
        // 3. own ds_writes visible, then sync (NO vmcnt drain of prefetch)
        asm volatile("s_waitcnt lgkmcnt(0)" ::: "memory");
        __builtin_amdgcn_s_barrier();
        __builtin_amdgcn_sched_barrier(0);
        // 4. MFMA from Sb / Vb[cur] with XOR-swizzled fragment reads
        {
            const char* Sbase = (const char*)Sb;
            const char* Vbase = (const char*)&Vb[cur][0];
            int swz_l = (lr & 7) << 4;
#pragma unroll
            for (int ks = 0; ks < 2; ++ks) {
                bf16x8 a[4], bb[4];
#pragma unroll
                for (int i = 0; i < 4; ++i) {
                    int r = rbase + 16 * i + lr;
                    a[i] = *(const bf16x8*)(Sbase + r * 128 + ((ks * 64 + q * 16) ^ swz_l));
                }
#pragma unroll
                for (int j = 0; j < 4; ++j) {
                    int d = cbase + 16 * j + lr;
                    bb[j] = *(const bf16x8*)(Vbase + d * 128 + ((ks * 64 + q * 16) ^ swz_l));
                }
#pragma unroll
                for (int i = 0; i < 4; ++i)
#pragma unroll
                    for (int j = 0; j < 4; ++j)
                        acc[i][j] = __builtin_amdgcn_mfma_f32_16x16x32_bf16(
                            a[i], bb[j], acc[i][j], 0, 0, 0);
            }
        }
        // 5. protect Sb / Vb[cur^1] from next iteration's overwrite
        __builtin_amdgcn_s_barrier();
        __builtin_amdgcn_sched_barrier(0);
    }

    float* ob = out + ((size_t)(b * T_ + t)) * N_ * D_;
#pragma unroll
    for (int i = 0; i < 4; ++i) {
#pragma unroll
        for (int j = 0; j < 4; ++j) {
            int row0 = n0 + rbase + 16 * i + q * 4;
            int col = cbase + 16 * j + lr;
#pragma unroll
            for (int e = 0; e < 4; ++e)
                ob[(size_t)(row0 + e) * D_ + col] = acc[i][j][e];
        }
    }
}

// ---------------------------------------------------------------------------
extern "C" void kernel_launch(void* const* d_in, const int* in_sizes, int n_in,
                              void* d_out, int out_size, void* d_ws, size_t ws_size,
                              hipStream_t stream) {
    const float* value = (const float*)d_in[0];
    const float* emb   = (const float*)d_in[1];
    const int*   mask  = (const int*)d_in[2];
    const float* Wqk   = (const float*)d_in[3];
    const float* bqk   = (const float*)d_in[4];
    const float* Wv    = (const float*)d_in[5];
    const float* bvv   = (const float*)d_in[6];
    float* out = (float*)d_out;

    float* ws = (float*)d_ws;
    float*          qkf  = ws;                                // 786432 f
    unsigned short* qb   = (unsigned short*)(ws + 786432);    // 786432 u16
    unsigned short* kNb  = (unsigned short*)(ws + 1179648);   // 786432 u16
    unsigned short* scb  = (unsigned short*)(ws + 1572864);   // 3145728 u16
    unsigned short* vtb  = (unsigned short*)(ws + 3145728);   // 12582912 u16
    unsigned short* WvTb = (unsigned short*)(ws + 9437184);   // 16384 u16
    unsigned*       mbp  = (unsigned*)(ws + 9445376);         // 131072 u32

    kA1W<<<6272, 128, 0, stream>>>(emb, Wqk, bqk, qkf, qb, Wv, WvTb);
    kA2n<<<192, 256, 0, stream>>>(qkf, kNb);
    kF<<<1472, 256, 0, stream>>>(qb, kNb, scb, value, WvTb, bvv, vtb, mask, mbp);
    kC<<<dim3(4, T_, B_), 256, 0, stream>>>(scb, mbp, vtb, out);
}

// Round 3
// 160.473 us; speedup vs baseline: 1.2366x; 1.0082x over previous
//
#include <hip/hip_runtime.h>

#define B_ 16
#define T_ 12
#define N_ 512
#define D_ 128
#define E_ 32

typedef __attribute__((ext_vector_type(8))) unsigned short u16x8;
typedef __attribute__((ext_vector_type(8))) __bf16 bf16x8;
typedef __attribute__((ext_vector_type(4))) float f32x4;

static __device__ __forceinline__ unsigned short f2bf(float f) {
    unsigned u = __float_as_uint(f);
    unsigned r = (u + 0x7fffu + ((u >> 16) & 1u)) >> 16;
    return (unsigned short)r;
}

static __device__ __forceinline__ void gld16(const void* src, void* dst) {
    __builtin_amdgcn_global_load_lds(
        (const __attribute__((address_space(1))) unsigned*)src,
        (__attribute__((address_space(3))) unsigned*)dst, 16, 0, 0);
}

// ---------------------------------------------------------------------------
// kA1: blocks [0,768):    qk = emb @ W_qk + b_qk (fp32) + q=softmax_D -> bf16.
//                         1 wave = 1 (t,n) row (2 d/lane), 4 rows/wave,
//                         Wqk held in 64 VGPR, softmax = shfl butterfly,
//                         ZERO barriers.
//      blocks [768,896):  WvT[d][k] = bf16(Wv[k][d])
//      blocks [896,1920): mask -> packed bitwords (moved here from kF)
// ---------------------------------------------------------------------------
__global__ __launch_bounds__(128) void kA1(const float* __restrict__ emb,
                                           const float* __restrict__ Wqk,
                                           const float* __restrict__ bqk,
                                           float* __restrict__ qk,
                                           unsigned short* __restrict__ qb,
                                           const float* __restrict__ Wv,
                                           unsigned short* __restrict__ WvT,
                                           const int* __restrict__ mask,
                                           unsigned* __restrict__ mb) {
    int bid = blockIdx.x;
    int tid = threadIdx.x;
    if (bid >= 896) {  // ---- mask pack ----
        int o = (bid - 896) * 128 + tid;  // 0..131071
        const int* mp = mask + (size_t)o * 32;
        unsigned bits = 0;
#pragma unroll
        for (int j = 0; j < 32; j += 4) {
            int4 m4 = *(const int4*)&mp[j];
            bits |= (m4.x ? 1u : 0u) << j;
            bits |= (m4.y ? 1u : 0u) << (j + 1);
            bits |= (m4.z ? 1u : 0u) << (j + 2);
            bits |= (m4.w ? 1u : 0u) << (j + 3);
        }
        mb[o] = bits;
        return;
    }
    if (bid >= 768) {  // ---- WvT ----
        int i = (bid - 768) * 128 + tid;  // 0..16383
        int d = i >> 7, k = i & 127;
        WvT[d * 128 + k] = f2bf(Wv[k * 128 + d]);
        return;
    }
    // ---- qk projection + softmax over D ----
    int w = tid >> 6, l = tid & 63;
    float wq0[E_], wq1[E_];
#pragma unroll
    for (int e = 0; e < E_; ++e) {
        wq0[e] = Wqk[e * D_ + l];
        wq1[e] = Wqk[e * D_ + l + 64];
    }
    float b0 = bqk[l], b1 = bqk[l + 64];
    for (int rr = 0; rr < 4; ++rr) {
        int tn = bid * 8 + w * 4 + rr;  // wave-uniform
        const float* ep = emb + (size_t)tn * E_;
        float a0 = b0, a1 = b1;
#pragma unroll
        for (int e = 0; e < E_; ++e) {
            float ev = ep[e];  // wave-uniform -> scalar load
            a0 = fmaf(ev, wq0[e], a0);
            a1 = fmaf(ev, wq1[e], a1);
        }
        qk[(size_t)tn * D_ + l] = a0;
        qk[(size_t)tn * D_ + l + 64] = a1;
        float mx = fmaxf(a0, a1);
#pragma unroll
        for (int s = 32; s > 0; s >>= 1) mx = fmaxf(mx, __shfl_xor(mx, s));
        float e0 = __expf(a0 - mx), e1 = __expf(a1 - mx);
        float sum = e0 + e1;
#pragma unroll
        for (int s = 32; s > 0; s >>= 1) sum += __shfl_xor(sum, s);
        float inv = 1.f / sum;
        qb[(size_t)tn * D_ + l] = f2bf(e0 * inv);
        qb[(size_t)tn * D_ + l + 64] = f2bf(e1 * inv);
    }
}

// ---------------------------------------------------------------------------
// kA2n: kN[t,n,d] = softmax over n of qk[t,n,d], kept [n][d], bf16. (anchor)
// ---------------------------------------------------------------------------
__global__ __launch_bounds__(256) void kA2n(const float* __restrict__ qk,
                                            unsigned short* __restrict__ kN) {
    int t = blockIdx.x >> 4;
    int d0 = (blockIdx.x & 15) * 8;
    int tid = threadIdx.x;
    int dc = tid & 7, ni = tid >> 3;  // ni 0..31
    const float* base = qk + (size_t)t * N_ * D_ + d0 + dc;
    float vals[16];
    float mx = -1e30f;
#pragma unroll
    for (int j = 0; j < 16; ++j) {
        vals[j] = base[(size_t)(ni + 32 * j) * D_];
        mx = fmaxf(mx, vals[j]);
    }
#pragma unroll
    for (int s = 8; s < 64; s <<= 1) mx = fmaxf(mx, __shfl_xor(mx, s));
    __shared__ float red[2][4][8];
    int wv = tid >> 6;
    if ((tid & 63) < 8) red[0][wv][dc] = mx;
    __syncthreads();
    mx = fmaxf(fmaxf(red[0][0][dc], red[0][1][dc]),
               fmaxf(red[0][2][dc], red[0][3][dc]));
    float sum = 0.f;
#pragma unroll
    for (int j = 0; j < 16; ++j) {
        vals[j] = __expf(vals[j] - mx);
        sum += vals[j];
    }
#pragma unroll
    for (int s = 8; s < 64; s <<= 1) sum += __shfl_xor(sum, s);
    if ((tid & 63) < 8) red[1][wv][dc] = sum;
    __syncthreads();
    sum = red[1][0][dc] + red[1][1][dc] + red[1][2][dc] + red[1][3][dc];
    float inv = 1.f / sum;
    unsigned short* op = kN + (size_t)t * N_ * D_ + d0 + dc;
#pragma unroll
    for (int j = 0; j < 16; ++j)
        op[(size_t)(ni + 32 * j) * D_] = f2bf(vals[j] * inv);
}

// ---------------------------------------------------------------------------
// kF: single-phase full-K=128 MFMA tiles. LDS 64 KB (2x 32KB), 2 blocks/CU.
//  blocks [0,192):   A3m: sc[t,n,m] = qb @ kN^T — both tiles via gload_lds
//                    with pre-swizzled global source (4-bit XOR swizzle).
//  blocks [192,960): Bm: vT[bt][d][m] = WvT @ value^T + bv — WvT via
//                    gload_lds; value fp32 loaded first (coalesced float4),
//                    converted, swizzle-written to LDS.
// One vmcnt(0)+barrier per block, then 64 MFMAs/wave straight.
// ---------------------------------------------------------------------------
__global__ __launch_bounds__(256, 2) void kF(const unsigned short* __restrict__ qb,
                                             const unsigned short* __restrict__ kN,
                                             unsigned short* __restrict__ sc,
                                             const float* __restrict__ value,
                                             const unsigned short* __restrict__ WvT,
                                             const float* __restrict__ bv,
                                             unsigned short* __restrict__ vT) {
    __shared__ unsigned short shA[128 * 128];  // 32 KB
    __shared__ unsigned short shB[128 * 128];  // 32 KB
    int bid = blockIdx.x;
    int tid = threadIdx.x;
    int wave = tid >> 6, lane = tid & 63;
    int q = lane >> 4, lr = lane & 15;
    int rbase = (wave & 1) * 64, cbase = (wave >> 1) * 64;
    int il = lane >> 4, i16 = lane & 15;

    f32x4 acc[4][4];
#pragma unroll
    for (int i = 0; i < 4; ++i)
#pragma unroll
        for (int j = 0; j < 4; ++j) acc[i][j] = (f32x4){0.f, 0.f, 0.f, 0.f};

    if (bid < 192) {  // ---- A3m ----
        int mt = bid & 3, nt = (bid >> 2) & 3, t = bid >> 4;
        int n0 = nt * 128, m0 = mt * 128;
        const char* qp = (const char*)(qb + (size_t)t * N_ * D_ + (size_t)n0 * D_);
        const char* kp = (const char*)(kN + (size_t)t * N_ * D_ + (size_t)m0 * D_);
#pragma unroll
        for (int it = 0; it < 8; ++it) {
            int r = it * 16 + wave * 4 + il;
            int si = (i16 * 16) ^ ((r & 15) << 4);
            char* dA = (char*)shA + (it * 16 + wave * 4) * 256 + lane * 16;
            char* dB = (char*)shB + (it * 16 + wave * 4) * 256 + lane * 16;
            gld16(qp + (size_t)r * 256 + si, dA);
            gld16(kp + (size_t)r * 256 + si, dB);
        }
        asm volatile("s_waitcnt vmcnt(0)" ::: "memory");
        __builtin_amdgcn_s_barrier();
        const char* Ab = (const char*)shA;
        const char* Bb = (const char*)shB;
#pragma unroll
        for (int ks = 0; ks < 4; ++ks) {
            bf16x8 a[4], b[4];
#pragma unroll
            for (int i = 0; i < 4; ++i) {
                int r = rbase + 16 * i + lr;
                a[i] = *(const bf16x8*)(Ab + r * 256 + ((ks * 64 + q * 16) ^ ((r & 15) << 4)));
            }
#pragma unroll
            for (int j = 0; j < 4; ++j) {
                int r = cbase + 16 * j + lr;
                b[j] = *(const bf16x8*)(Bb + r * 256 + ((ks * 64 + q * 16) ^ ((r & 15) << 4)));
            }
#pragma unroll
            for (int i = 0; i < 4; ++i)
#pragma unroll
                for (int j = 0; j < 4; ++j)
                    acc[i][j] = __builtin_amdgcn_mfma_f32_16x16x32_bf16(
                        a[i], b[j], acc[i][j], 0, 0, 0);
        }
        unsigned short* sp = sc + (size_t)t * N_ * N_;
#pragma unroll
        for (int i = 0; i < 4; ++i)
#pragma unroll
            for (int j = 0; j < 4; ++j) {
                int row0 = n0 + rbase + 16 * i + q * 4;
                int col = m0 + cbase + 16 * j + lr;
#pragma unroll
                for (int e = 0; e < 4; ++e)
                    sp[(size_t)(row0 + e) * N_ + col] = f2bf(acc[i][j][e]);
            }
        return;
    }

    // ---- Bm ----
    {
        int idx = bid - 192;
        int mt = idx & 3, bt = idx >> 2;
        int m0 = mt * 128;
        const float* vp = value + ((size_t)bt * N_ + m0) * D_;
        const char* wp = (const char*)WvT;

        // 1. issue coalesced fp32 value loads first (16 float4/thread)
        int g = tid >> 4, c16 = tid & 15;
        float4 vv[16];
#pragma unroll
        for (int j = 0; j < 16; ++j) {
            int r = g * 8 + (j >> 1);
            int kf = (j & 1) * 64 + c16 * 4;
            vv[j] = *(const float4*)(vp + (size_t)r * D_ + kf);
        }
        // 2. issue WvT gload_lds (completes independently)
#pragma unroll
        for (int it = 0; it < 8; ++it) {
            int r = it * 16 + wave * 4 + il;
            int si = (i16 * 16) ^ ((r & 15) << 4);
            char* dA = (char*)shA + (it * 16 + wave * 4) * 256 + lane * 16;
            gld16(wp + (size_t)r * 256 + si, dA);
        }
        // 3. convert + swizzled ds_write of value tile
#pragma unroll
        for (int j = 0; j < 16; ++j) {
            int r = g * 8 + (j >> 1);
            int kb = (j & 1) * 128 + c16 * 8;
            ushort4 o;
            o.x = f2bf(vv[j].x); o.y = f2bf(vv[j].y);
            o.z = f2bf(vv[j].z); o.w = f2bf(vv[j].w);
            *(ushort4*)((char*)shB + r * 256 + (kb ^ ((r & 15) << 4))) = o;
        }
        asm volatile("s_waitcnt vmcnt(0) lgkmcnt(0)" ::: "memory");
        __builtin_amdgcn_s_barrier();
        const char* Ab = (const char*)shA;
        const char* Bb = (const char*)shB;
#pragma unroll
        for (int ks = 0; ks < 4; ++ks) {
            bf16x8 a[4], b[4];
#pragma unroll
            for (int i = 0; i < 4; ++i) {
                int r = rbase + 16 * i + lr;
                a[i] = *(const bf16x8*)(Ab + r * 256 + ((ks * 64 + q * 16) ^ ((r & 15) << 4)));
            }
#pragma unroll
            for (int j = 0; j < 4; ++j) {
                int r = cbase + 16 * j + lr;
                b[j] = *(const bf16x8*)(Bb + r * 256 + ((ks * 64 + q * 16) ^ ((r & 15) << 4)));
            }
#pragma unroll
            for (int i = 0; i < 4; ++i)
#pragma unroll
                for (int j = 0; j < 4; ++j)
                    acc[i][j] = __builtin_amdgcn_mfma_f32_16x16x32_bf16(
                        a[i], b[j], acc[i][j], 0, 0, 0);
        }
        unsigned short* op = vT + (size_t)bt * N_ * D_;
#pragma unroll
        for (int i = 0; i < 4; ++i) {
            int row0 = rbase + 16 * i + q * 4;
            float4 bq = *(const float4*)&bv[row0];
#pragma unroll
            for (int j = 0; j < 4; ++j) {
                int col = m0 + cbase + 16 * j + lr;
                op[(size_t)(row0 + 0) * N_ + col] = f2bf(acc[i][j][0] + bq.x);
                op[(size_t)(row0 + 1) * N_ + col] = f2bf(acc[i][j][1] + bq.y);
                op[(size_t)(row0 + 2) * N_ + col] = f2bf(acc[i][j][2] + bq.z);
                op[(size_t)(row0 + 3) * N_ + col] = f2bf(acc[i][j][3] + bq.w);
            }
        }
    }
}

// ---------------------------------------------------------------------------
// kC: out[b,t,n,d] = sum_m (mask ? score0 : -1e9) * v[b,t,m,d]  (anchor, r2)
// ---------------------------------------------------------------------------
__global__ __launch_bounds__(256, 3) void kC(const unsigned short* __restrict__ sc,
                                             const unsigned* __restrict__ mb,
                                             const unsigned short* __restrict__ vT,
                                             float* __restrict__ out) {
    int n0 = blockIdx.x * 128;
    int t = blockIdx.y, b = blockIdx.z;
    int tid = threadIdx.x;
    int wave = tid >> 6, lane = tid & 63;
    int q = lane >> 4, lr = lane & 15;
    int rbase = (wave & 1) * 64, cbase = (wave >> 1) * 64;

    __shared__ unsigned short Sb[128 * 64];
    __shared__ unsigned short Vb[2][128 * 64];

    const unsigned short* scp = sc + (size_t)t * N_ * N_ + (size_t)n0 * N_;
    const unsigned short* vtp = vT + ((size_t)(b * T_ + t)) * N_ * D_;  // [d][m]
    const unsigned* mbp = mb + ((size_t)b * N_ + n0) * 16;
    const unsigned short NEG = 0xCE6E;  // bf16(-1e9)

    f32x4 acc[4][4];
#pragma unroll
    for (int i = 0; i < 4; ++i)
#pragma unroll
        for (int j = 0; j < 4; ++j) acc[i][j] = (f32x4){0.f, 0.f, 0.f, 0.f};

    int sr = tid >> 1, sh2 = tid & 1;
    const unsigned short* sg = scp + (size_t)sr * N_ + sh2 * 32;
    const unsigned* mwp = mbp + sr * 16 + sh2;
    int swz_r = (sr & 7) << 4;
    char* Sw[4];
#pragma unroll
    for (int p = 0; p < 4; ++p)
        Sw[p] = (char*)Sb + sr * 128 + ((sh2 * 64 + p * 16) ^ swz_r);

    int l3 = lane >> 3, l7 = lane & 7;
    int vin = (l7 * 16) ^ (l3 << 4);
    const char* vbase = (const char*)vtp;

#pragma unroll
    for (int it = 0; it < 4; ++it) {
        int row = (it * 4 + wave) * 8 + l3;
        const char* src = vbase + (size_t)row * 1024 + vin;
        char* dst = (char*)&Vb[0][0] + ((it * 4 + wave) * 64 + lane) * 16;
        gld16(src, dst);
    }
    u16x8 sreg[4];
    unsigned mw;
#pragma unroll
    for (int p = 0; p < 4; ++p) sreg[p] = *(const u16x8*)(sg + p * 8);
    mw = mwp[0];

    for (int kc = 0; kc < 8; ++kc) {
        int cur = kc & 1;
#pragma unroll
        for (int p = 0; p < 4; ++p) {
            unsigned bits = mw >> (p * 8);
            u16x8 o;
#pragma unroll
            for (int j = 0; j < 8; ++j)
                o[j] = ((bits >> j) & 1u) ? sreg[p][j] : NEG;
            *(u16x8*)Sw[p] = o;
        }
        if (kc < 7) {
            int off = (kc + 1) * 128;
#pragma unroll
            for (int it = 0; it < 4; ++it) {
                int row = (it * 4 + wave) * 8 + l3;
                const char* src = vbase + (size_t)row * 1024 + off + vin;
                char* dst = (char*)&Vb[cur ^ 1][0] + ((it * 4 + wave) * 64 + lane) * 16;
                gld16(src, dst);
            }
            int eoff = (kc + 1) * 64;
#pragma unroll
            for (int p = 0; p < 4; ++p) sreg[p] = *(const u16x8*)(sg + eoff + p * 8);
            mw = mwp[(kc + 1) * 2];
        }
        asm volatile("s_waitcnt lgkmcnt(0)" ::: "memory");
        __builtin_amdgcn_s_barrier();
        __builtin_amdgcn_sched_barrier(0);
        {
            const char* Sbase = (const char*)Sb;
            const char* Vbase = (const char*)&Vb[cur][0];
            int swz_l = (lr & 7) << 4;
#pragma unroll
            for (int ks = 0; ks < 2; ++ks) {
                bf16x8 a[4], bb[4];
#pragma unroll
                for (int i = 0; i < 4; ++i) {
                    int r = rbase + 16 * i + lr;
                    a[i] = *(const bf16x8*)(Sbase + r * 128 + ((ks * 64 + q * 16) ^ swz_l));
                }
#pragma unroll
                for (int j = 0; j < 4; ++j) {
                    int d = cbase + 16 * j + lr;
                    bb[j] = *(const bf16x8*)(Vbase + d * 128 + ((ks * 64 + q * 16) ^ swz_l));
                }
#pragma unroll
                for (int i = 0; i < 4; ++i)
#pragma unroll
                    for (int j = 0; j < 4; ++j)
                        acc[i][j] = __builtin_amdgcn_mfma_f32_16x16x32_bf16(
                            a[i], bb[j], acc[i][j], 0, 0, 0);
            }
        }
        __builtin_amdgcn_s_barrier();
        __builtin_amdgcn_sched_barrier(0);
    }

    float* ob = out + ((size_t)(b * T_ + t)) * N_ * D_;
#pragma unroll
    for (int i = 0; i < 4; ++i) {
#pragma unroll
        for (int j = 0; j < 4; ++j) {
            int row0 = n0 + rbase + 16 * i + q * 4;
            int col = cbase + 16 * j + lr;
#pragma unroll
            for (int e = 0; e < 4; ++e)
                ob[(size_t)(row0 + e) * D_ + col] = acc[i][j][e];
        }
    }
}

// ---------------------------------------------------------------------------
extern "C" void kernel_launch(void* const* d_in, const int* in_sizes, int n_in,
                              void* d_out, int out_size, void* d_ws, size_t ws_size,
                              hipStream_t stream) {
    const float* value = (const float*)d_in[0];
    const float* emb   = (const float*)d_in[1];
    const int*   mask  = (const int*)d_in[2];
    const float* Wqk   = (const float*)d_in[3];
    const float* bqk   = (const float*)d_in[4];
    const float* Wv    = (const float*)d_in[5];
    const float* bvv   = (const float*)d_in[6];
    float* out = (float*)d_out;

    float* ws = (float*)d_ws;
    float*          qkf  = ws;                                // 786432 f
    unsigned short* qb   = (unsigned short*)(ws + 786432);    // 786432 u16
    unsigned short* kNb  = (unsigned short*)(ws + 1179648);   // 786432 u16
    unsigned short* scb  = (unsigned short*)(ws + 1572864);   // 3145728 u16
    unsigned short* vtb  = (unsigned short*)(ws + 3145728);   // 12582912 u16
    unsigned short* WvTb = (unsigned short*)(ws + 9437184);   // 16384 u16
    unsigned*       mbp  = (unsigned*)(ws + 9445376);         // 131072 u32

    kA1<<<1920, 128, 0, stream>>>(emb, Wqk, bqk, qkf, qb, Wv, WvTb, mask, mbp);
    kA2n<<<192, 256, 0, stream>>>(qkf, kNb);
    kF<<<960, 256, 0, stream>>>(qb, kNb, scb, value, WvTb, bvv, vtb);
    kC<<<dim3(4, T_, B_), 256, 0, stream>>>(scb, mbp, vtb, out);
}

// Round 4
// 157.283 us; speedup vs baseline: 1.2617x; 1.0203x over previous
//
#include <hip/hip_runtime.h>

#define B_ 16
#define T_ 12
#define N_ 512
#define D_ 128
#define E_ 32

typedef __attribute__((ext_vector_type(8))) unsigned short u16x8;
typedef __attribute__((ext_vector_type(8))) __bf16 bf16x8;
typedef __attribute__((ext_vector_type(4))) float f32x4;

static __device__ __forceinline__ unsigned short f2bf(float f) {
    unsigned u = __float_as_uint(f);
    unsigned r = (u + 0x7fffu + ((u >> 16) & 1u)) >> 16;
    return (unsigned short)r;
}

static __device__ __forceinline__ void gld16(const void* src, void* dst) {
    __builtin_amdgcn_global_load_lds(
        (const __attribute__((address_space(1))) unsigned*)src,
        (__attribute__((address_space(3))) unsigned*)dst, 16, 0, 0);
}

// ---------------------------------------------------------------------------
// k1: ALL input-only stages in one wide launch (no inter-stage deps):
//  [0,192):     kN: recompute qk[t,:,d8] from emb in-block (emb staged in
//               swizzled LDS), softmax over n -> kN bf16. No qk round-trip.
//  [192,576):   qProj: qk row + softmax over D -> qb bf16. Wave-autonomous,
//               zero barriers. (qk recomputed, not stored.)
//  [576,1088):  mask -> packed bitwords
//  [1088,1152): WvT[d][k] = bf16(Wv[k][d])
// ---------------------------------------------------------------------------
__global__ __launch_bounds__(256) void k1(const float* __restrict__ emb,
                                          const float* __restrict__ Wqk,
                                          const float* __restrict__ bqk,
                                          unsigned short* __restrict__ qb,
                                          unsigned short* __restrict__ kN,
                                          const float* __restrict__ Wv,
                                          unsigned short* __restrict__ WvT,
                                          const int* __restrict__ mask,
                                          unsigned* __restrict__ mb) {
    __shared__ __align__(16) char LE[256 * 128];  // 32 KB: 256 emb rows swizzled
    __shared__ float red[2][4][8];
    int bid = blockIdx.x;
    int tid = threadIdx.x;

    if (bid < 192) {  // ---- kN: softmax over n ----
        int t = bid >> 4;
        int d0 = (bid & 15) * 8;
        int dc = tid & 7, ni = tid >> 3;  // ni 0..31
        float wqv[E_];
#pragma unroll
        for (int e = 0; e < E_; ++e) wqv[e] = Wqk[e * D_ + d0 + dc];
        float bq = bqk[d0 + dc];
        const float4* eb4 = (const float4*)(emb + (size_t)t * N_ * E_);

        float4 st0[8], st1[8];
#pragma unroll
        for (int ii = 0; ii < 8; ++ii) st0[ii] = eb4[ii * 256 + tid];
        // swizzled write of chunk 0 (rows n in [0,256))
#pragma unroll
        for (int ii = 0; ii < 8; ++ii) {
            int f = ii * 256 + tid;
            int n = f >> 3, s = f & 7;
            *(float4*)(LE + n * 128 + ((s * 16) ^ ((n & 7) << 4))) = st0[ii];
        }
        // issue chunk-1 loads early (hide HBM under chunk-0 compute)
#pragma unroll
        for (int ii = 0; ii < 8; ++ii) st1[ii] = eb4[2048 + ii * 256 + tid];
        __syncthreads();

        float vals[16];
#pragma unroll
        for (int jj = 0; jj < 8; ++jj) {
            int n = ni + 32 * jj;
            float a = bq;
#pragma unroll
            for (int s = 0; s < 8; ++s) {
                f32x4 ev = *(const f32x4*)(LE + n * 128 + ((s * 16) ^ ((n & 7) << 4)));
                a = fmaf(ev[0], wqv[s * 4 + 0], a);
                a = fmaf(ev[1], wqv[s * 4 + 1], a);
                a = fmaf(ev[2], wqv[s * 4 + 2], a);
                a = fmaf(ev[3], wqv[s * 4 + 3], a);
            }
            vals[jj] = a;
        }
        __syncthreads();
#pragma unroll
        for (int ii = 0; ii < 8; ++ii) {
            int f = ii * 256 + tid;
            int n = f >> 3, s = f & 7;
            *(float4*)(LE + n * 128 + ((s * 16) ^ ((n & 7) << 4))) = st1[ii];
        }
        __syncthreads();
#pragma unroll
        for (int jj = 0; jj < 8; ++jj) {
            int n = ni + 32 * jj;
            float a = bq;
#pragma unroll
            for (int s = 0; s < 8; ++s) {
                f32x4 ev = *(const f32x4*)(LE + n * 128 + ((s * 16) ^ ((n & 7) << 4)));
                a = fmaf(ev[0], wqv[s * 4 + 0], a);
                a = fmaf(ev[1], wqv[s * 4 + 1], a);
                a = fmaf(ev[2], wqv[s * 4 + 2], a);
                a = fmaf(ev[3], wqv[s * 4 + 3], a);
            }
            vals[8 + jj] = a;
        }

        float mx = -1e30f;
#pragma unroll
        for (int j = 0; j < 16; ++j) mx = fmaxf(mx, vals[j]);
#pragma unroll
        for (int s = 8; s < 64; s <<= 1) mx = fmaxf(mx, __shfl_xor(mx, s));
        int wv = tid >> 6;
        if ((tid & 63) < 8) red[0][wv][dc] = mx;
        __syncthreads();
        mx = fmaxf(fmaxf(red[0][0][dc], red[0][1][dc]),
                   fmaxf(red[0][2][dc], red[0][3][dc]));
        float sum = 0.f;
#pragma unroll
        for (int j = 0; j < 16; ++j) {
            vals[j] = __expf(vals[j] - mx);
            sum += vals[j];
        }
#pragma unroll
        for (int s = 8; s < 64; s <<= 1) sum += __shfl_xor(sum, s);
        if ((tid & 63) < 8) red[1][wv][dc] = sum;
        __syncthreads();
        sum = red[1][0][dc] + red[1][1][dc] + red[1][2][dc] + red[1][3][dc];
        float inv = 1.f / sum;
        unsigned short* op = kN + (size_t)t * N_ * D_ + d0 + dc;
#pragma unroll
        for (int j = 0; j < 16; ++j)
            op[(size_t)(ni + 32 * j) * D_] = f2bf(vals[j] * inv);
        return;
    }

    if (bid < 576) {  // ---- qProj + softmax over D ----
        int bid2 = bid - 192;
        int w = tid >> 6, l = tid & 63;
        float wq0[E_], wq1[E_];
#pragma unroll
        for (int e = 0; e < E_; ++e) {
            wq0[e] = Wqk[e * D_ + l];
            wq1[e] = Wqk[e * D_ + l + 64];
        }
        float b0 = bqk[l], b1 = bqk[l + 64];
        for (int rr = 0; rr < 4; ++rr) {
            int tn = bid2 * 16 + w * 4 + rr;  // wave-uniform
            const float* ep = emb + (size_t)tn * E_;
            float a0 = b0, a1 = b1;
#pragma unroll
            for (int e = 0; e < E_; ++e) {
                float ev = ep[e];
                a0 = fmaf(ev, wq0[e], a0);
                a1 = fmaf(ev, wq1[e], a1);
            }
            float mx = fmaxf(a0, a1);
#pragma unroll
            for (int s = 32; s > 0; s >>= 1) mx = fmaxf(mx, __shfl_xor(mx, s));
            float e0 = __expf(a0 - mx), e1 = __expf(a1 - mx);
            float sum = e0 + e1;
#pragma unroll
            for (int s = 32; s > 0; s >>= 1) sum += __shfl_xor(sum, s);
            float inv = 1.f / sum;
            qb[(size_t)tn * D_ + l] = f2bf(e0 * inv);
            qb[(size_t)tn * D_ + l + 64] = f2bf(e1 * inv);
        }
        return;
    }

    if (bid < 1088) {  // ---- mask pack ----
        int o = (bid - 576) * 256 + tid;  // 0..131071
        const int* mp = mask + (size_t)o * 32;
        unsigned bits = 0;
#pragma unroll
        for (int j = 0; j < 32; j += 4) {
            int4 m4 = *(const int4*)&mp[j];
            bits |= (m4.x ? 1u : 0u) << j;
            bits |= (m4.y ? 1u : 0u) << (j + 1);
            bits |= (m4.z ? 1u : 0u) << (j + 2);
            bits |= (m4.w ? 1u : 0u) << (j + 3);
        }
        mb[o] = bits;
        return;
    }

    {  // ---- WvT ----
        int i = (bid - 1088) * 256 + tid;  // 0..16383
        int d = i >> 7, k = i & 127;
        WvT[d * 128 + k] = f2bf(Wv[k * 128 + d]);
    }
}

// ---------------------------------------------------------------------------
// kF: 2-chunk K-split pipeline (kC's proven geometry: 128-B LDS rows,
// (r&7)<<4 XOR swizzle, gload_lds with pre-swizzled source, counted vmcnt).
//  [0,192):   A3m: sc = qb @ kN^T
//  [192,960): Bm:  vT[bt][d][m] = WvT @ value^T + bv (value fp32 reg-staged)
// LDS 64 KB (chunk-separated [2][128][128B] per tile), 2 blocks/CU.
// ---------------------------------------------------------------------------
__global__ __launch_bounds__(256, 2) void kF(const unsigned short* __restrict__ qb,
                                             const unsigned short* __restrict__ kN,
                                             unsigned short* __restrict__ sc,
                                             const float* __restrict__ value,
                                             const unsigned short* __restrict__ WvT,
                                             const float* __restrict__ bv,
                                             unsigned short* __restrict__ vT) {
    __shared__ __align__(16) char LA[2][128 * 128];  // 32 KB (A tile, 2 chunks)
    __shared__ __align__(16) char LB[2][128 * 128];  // 32 KB (B tile, 2 chunks)
    int bid = blockIdx.x;
    int tid = threadIdx.x;
    int wave = tid >> 6, lane = tid & 63;
    int q = lane >> 4, lr = lane & 15;
    int rbase = (wave & 1) * 64, cbase = (wave >> 1) * 64;
    int l3 = lane >> 3, l7 = lane & 7;

    f32x4 acc[4][4];
#pragma unroll
    for (int i = 0; i < 4; ++i)
#pragma unroll
        for (int j = 0; j < 4; ++j) acc[i][j] = (f32x4){0.f, 0.f, 0.f, 0.f};

// stage one 16-KB chunk c of a [128][256B] global tile into lb (linear dst,
// pre-swizzled source): LDS[row][slot] = G[row][c*128 + (slot*16 ^ swz(row))]
#define STAGE_T(gbase, lb, c)                                                   \
    _Pragma("unroll") for (int it_ = 0; it_ < 4; ++it_) {                       \
        int row_ = it_ * 32 + wave * 8 + l3;                                    \
        gld16((gbase) + (size_t)row_ * 256 + (c) * 128 +                        \
                  ((l7 * 16) ^ ((row_ & 7) << 4)),                              \
              (lb) + (it_ * 32 + wave * 8) * 128 + lane * 16);                  \
    }

// 16 MFMAs on chunk c (K=64 as 2 sub-steps of 32)
#define MFMA_CHUNK(c)                                                           \
    _Pragma("unroll") for (int ksl_ = 0; ksl_ < 2; ++ksl_) {                    \
        bf16x8 a_[4], b_[4];                                                    \
        _Pragma("unroll") for (int i_ = 0; i_ < 4; ++i_) {                      \
            int r_ = rbase + 16 * i_ + lr;                                      \
            a_[i_] = *(const bf16x8*)(LA[c] + r_ * 128 +                        \
                                      ((ksl_ * 64 + q * 16) ^ ((r_ & 7) << 4)));\
        }                                                                       \
        _Pragma("unroll") for (int j_ = 0; j_ < 4; ++j_) {                      \
            int r_ = cbase + 16 * j_ + lr;                                      \
            b_[j_] = *(const bf16x8*)(LB[c] + r_ * 128 +                        \
                                      ((ksl_ * 64 + q * 16) ^ ((r_ & 7) << 4)));\
        }                                                                       \
        _Pragma("unroll") for (int i_ = 0; i_ < 4; ++i_)                        \
            _Pragma("unroll") for (int j_ = 0; j_ < 4; ++j_)                    \
                acc[i_][j_] = __builtin_amdgcn_mfma_f32_16x16x32_bf16(          \
                    a_[i_], b_[j_], acc[i_][j_], 0, 0, 0);                      \
    }

    if (bid < 192) {  // ---- A3m ----
        int mt = bid & 3, nt = (bid >> 2) & 3, t = bid >> 4;
        int n0 = nt * 128, m0 = mt * 128;
        const char* qp = (const char*)(qb + (size_t)t * N_ * D_ + (size_t)n0 * D_);
        const char* kp = (const char*)(kN + (size_t)t * N_ * D_ + (size_t)m0 * D_);
        STAGE_T(qp, LA[0], 0)
        STAGE_T(kp, LB[0], 0)
        STAGE_T(qp, LA[1], 1)
        STAGE_T(kp, LB[1], 1)
        // chunk0 done when <=8 of this wave's 16 gld16 outstanding
        asm volatile("s_waitcnt vmcnt(8)" ::: "memory");
        __builtin_amdgcn_sched_barrier(0);
        __builtin_amdgcn_s_barrier();
        __builtin_amdgcn_sched_barrier(0);
        MFMA_CHUNK(0)
        asm volatile("s_waitcnt vmcnt(0)" ::: "memory");
        __builtin_amdgcn_sched_barrier(0);
        __builtin_amdgcn_s_barrier();
        __builtin_amdgcn_sched_barrier(0);
        MFMA_CHUNK(1)

        unsigned short* sp = sc + (size_t)t * N_ * N_;
#pragma unroll
        for (int i = 0; i < 4; ++i)
#pragma unroll
            for (int j = 0; j < 4; ++j) {
                int row0 = n0 + rbase + 16 * i + q * 4;
                int col = m0 + cbase + 16 * j + lr;
#pragma unroll
                for (int e = 0; e < 4; ++e)
                    sp[(size_t)(row0 + e) * N_ + col] = f2bf(acc[i][j][e]);
            }
        return;
    }

    // ---- Bm ----
    {
        int idx = bid - 192;
        int mt = idx & 3, bt = idx >> 2;
        int m0 = mt * 128;
        const float* vp = value + ((size_t)bt * N_ + m0) * D_;
        const char* wp = (const char*)WvT;
        int g = tid >> 4, c16 = tid & 15;

        float4 v0[8], v1[8];
        // pinned issue order: [val-c0(8), wvt-c0(4), val-c1(8), wvt-c1(4)]
#pragma unroll
        for (int jj = 0; jj < 8; ++jj)
            v0[jj] = *(const float4*)(vp + (size_t)(g * 8 + jj) * D_ + c16 * 4);
        __builtin_amdgcn_sched_barrier(0);
        STAGE_T(wp, LA[0], 0)
        __builtin_amdgcn_sched_barrier(0);
#pragma unroll
        for (int jj = 0; jj < 8; ++jj)
            v1[jj] = *(const float4*)(vp + (size_t)(g * 8 + jj) * D_ + 64 + c16 * 4);
        __builtin_amdgcn_sched_barrier(0);
        STAGE_T(wp, LA[1], 1)
        __builtin_amdgcn_sched_barrier(0);

        // convert+swizzled write of value chunk 0 (compiler waits v0)
#pragma unroll
        for (int jj = 0; jj < 8; ++jj) {
            int row = g * 8 + jj;
            ushort4 o;
            o.x = f2bf(v0[jj].x); o.y = f2bf(v0[jj].y);
            o.z = f2bf(v0[jj].z); o.w = f2bf(v0[jj].w);
            *(ushort4*)(LB[0] + row * 128 + ((c16 * 8) ^ ((row & 7) << 4))) = o;
        }
        // wvt-c0 done when <=12 outstanding (val-c1 + wvt-c1 still in flight)
        asm volatile("s_waitcnt vmcnt(12) lgkmcnt(0)" ::: "memory");
        __builtin_amdgcn_sched_barrier(0);
        __builtin_amdgcn_s_barrier();
        __builtin_amdgcn_sched_barrier(0);
        MFMA_CHUNK(0)
#pragma unroll
        for (int jj = 0; jj < 8; ++jj) {
            int row = g * 8 + jj;
            ushort4 o;
            o.x = f2bf(v1[jj].x); o.y = f2bf(v1[jj].y);
            o.z = f2bf(v1[jj].z); o.w = f2bf(v1[jj].w);
            *(ushort4*)(LB[1] + row * 128 + ((c16 * 8) ^ ((row & 7) << 4))) = o;
        }
        asm volatile("s_waitcnt vmcnt(0) lgkmcnt(0)" ::: "memory");
        __builtin_amdgcn_sched_barrier(0);
        __builtin_amdgcn_s_barrier();
        __builtin_amdgcn_sched_barrier(0);
        MFMA_CHUNK(1)

        unsigned short* op = vT + (size_t)bt * N_ * D_;
#pragma unroll
        for (int i = 0; i < 4; ++i) {
            int row0 = rbase + 16 * i + q * 4;
            float4 bq = *(const float4*)&bv[row0];
#pragma unroll
            for (int j = 0; j < 4; ++j) {
                int col = m0 + cbase + 16 * j + lr;
                op[(size_t)(row0 + 0) * N_ + col] = f2bf(acc[i][j][0] + bq.x);
                op[(size_t)(row0 + 1) * N_ + col] = f2bf(acc[i][j][1] + bq.y);
                op[(size_t)(row0 + 2) * N_ + col] = f2bf(acc[i][j][2] + bq.z);
                op[(size_t)(row0 + 3) * N_ + col] = f2bf(acc[i][j][3] + bq.w);
            }
        }
    }
#undef STAGE_T
#undef MFMA_CHUNK
}

// ---------------------------------------------------------------------------
// kC: out[b,t,n,d] = sum_m (mask ? score0 : -1e9) * v[b,t,m,d]  (anchor, r2)
// ---------------------------------------------------------------------------
__global__ __launch_bounds__(256, 3) void kC(const unsigned short* __restrict__ sc,
                                             const unsigned* __restrict__ mb,
                                             const unsigned short* __restrict__ vT,
                                             float* __restrict__ out) {
    int n0 = blockIdx.x * 128;
    int t = blockIdx.y, b = blockIdx.z;
    int tid = threadIdx.x;
    int wave = tid >> 6, lane = tid & 63;
    int q = lane >> 4, lr = lane & 15;
    int rbase = (wave & 1) * 64, cbase = (wave >> 1) * 64;

    __shared__ unsigned short Sb[128 * 64];
    __shared__ unsigned short Vb[2][128 * 64];

    const unsigned short* scp = sc + (size_t)t * N_ * N_ + (size_t)n0 * N_;
    const unsigned short* vtp = vT + ((size_t)(b * T_ + t)) * N_ * D_;  // [d][m]
    const unsigned* mbp = mb + ((size_t)b * N_ + n0) * 16;
    const unsigned short NEG = 0xCE6E;  // bf16(-1e9)

    f32x4 acc[4][4];
#pragma unroll
    for (int i = 0; i < 4; ++i)
#pragma unroll
        for (int j = 0; j < 4; ++j) acc[i][j] = (f32x4){0.f, 0.f, 0.f, 0.f};

    int sr = tid >> 1, sh2 = tid & 1;
    const unsigned short* sg = scp + (size_t)sr * N_ + sh2 * 32;
    const unsigned* mwp = mbp + sr * 16 + sh2;
    int swz_r = (sr & 7) << 4;
    char* Sw[4];
#pragma unroll
    for (int p = 0; p < 4; ++p)
        Sw[p] = (char*)Sb + sr * 128 + ((sh2 * 64 + p * 16) ^ swz_r);

    int l3 = lane >> 3, l7 = lane & 7;
    int vin = (l7 * 16) ^ (l3 << 4);
    const char* vbase = (const char*)vtp;

#pragma unroll
    for (int it = 0; it < 4; ++it) {
        int row = (it * 4 + wave) * 8 + l3;
        const char* src = vbase + (size_t)row * 1024 + vin;
        char* dst = (char*)&Vb[0][0] + ((it * 4 + wave) * 64 + lane) * 16;
        gld16(src, dst);
    }
    u16x8 sreg[4];
    unsigned mw;
#pragma unroll
    for (int p = 0; p < 4; ++p) sreg[p] = *(const u16x8*)(sg + p * 8);
    mw = mwp[0];

    for (int kc = 0; kc < 8; ++kc) {
        int cur = kc & 1;
#pragma unroll
        for (int p = 0; p < 4; ++p) {
            unsigned bits = mw >> (p * 8);
            u16x8 o;
#pragma unroll
            for (int j = 0; j < 8; ++j)
                o[j] = ((bits >> j) & 1u) ? sreg[p][j] : NEG;
            *(u16x8*)Sw[p] = o;
        }
        if (kc < 7) {
            int off = (kc + 1) * 128;
#pragma unroll
            for (int it = 0; it < 4; ++it) {
                int row = (it * 4 + wave) * 8 + l3;
                const char* src = vbase + (size_t)row * 1024 + off + vin;
                char* dst = (char*)&Vb[cur ^ 1][0] + ((it * 4 + wave) * 64 + lane) * 16;
                gld16(src, dst);
            }
            int eoff = (kc + 1) * 64;
#pragma unroll
            for (int p = 0; p < 4; ++p) sreg[p] = *(const u16x8*)(sg + eoff + p * 8);
            mw = mwp[(kc + 1) * 2];
        }
        asm volatile("s_waitcnt lgkmcnt(0)" ::: "memory");
        __builtin_amdgcn_s_barrier();
        __builtin_amdgcn_sched_barrier(0);
        {
            const char* Sbase = (const char*)Sb;
            const char* Vbase = (const char*)&Vb[cur][0];
            int swz_l = (lr & 7) << 4;
#pragma unroll
            for (int ks = 0; ks < 2; ++ks) {
                bf16x8 a[4], bb[4];
#pragma unroll
                for (int i = 0; i < 4; ++i) {
                    int r = rbase + 16 * i + lr;
                    a[i] = *(const bf16x8*)(Sbase + r * 128 + ((ks * 64 + q * 16) ^ swz_l));
                }
#pragma unroll
                for (int j = 0; j < 4; ++j) {
                    int d = cbase + 16 * j + lr;
                    bb[j] = *(const bf16x8*)(Vbase + d * 128 + ((ks * 64 + q * 16) ^ swz_l));
                }
#pragma unroll
                for (int i = 0; i < 4; ++i)
#pragma unroll
                    for (int j = 0; j < 4; ++j)
                        acc[i][j] = __builtin_amdgcn_mfma_f32_16x16x32_bf16(
                            a[i], bb[j], acc[i][j], 0, 0, 0);
            }
        }
        __builtin_amdgcn_s_barrier();
        __builtin_amdgcn_sched_barrier(0);
    }

    float* ob = out + ((size_t)(b * T_ + t)) * N_ * D_;
#pragma unroll
    for (int i = 0; i < 4; ++i) {
#pragma unroll
        for (int j = 0; j < 4; ++j) {
            int row0 = n0 + rbase + 16 * i + q * 4;
            int col = cbase + 16 * j + lr;
#pragma unroll
            for (int e = 0; e < 4; ++e)
                ob[(size_t)(row0 + e) * D_ + col] = acc[i][j][e];
        }
    }
}

// ---------------------------------------------------------------------------
extern "C" void kernel_launch(void* const* d_in, const int* in_sizes, int n_in,
                              void* d_out, int out_size, void* d_ws, size_t ws_size,
                              hipStream_t stream) {
    const float* value = (const float*)d_in[0];
    const float* emb   = (const float*)d_in[1];
    const int*   mask  = (const int*)d_in[2];
    const float* Wqk   = (const float*)d_in[3];
    const float* bqk   = (const float*)d_in[4];
    const float* Wv    = (const float*)d_in[5];
    const float* bvv   = (const float*)d_in[6];
    float* out = (float*)d_out;

    float* ws = (float*)d_ws;
    unsigned short* qb   = (unsigned short*)(ws + 786432);    // 786432 u16
    unsigned short* kNb  = (unsigned short*)(ws + 1179648);   // 786432 u16
    unsigned short* scb  = (unsigned short*)(ws + 1572864);   // 3145728 u16
    unsigned short* vtb  = (unsigned short*)(ws + 3145728);   // 12582912 u16
    unsigned short* WvTb = (unsigned short*)(ws + 9437184);   // 16384 u16
    unsigned*       mbp  = (unsigned*)(ws + 9445376);         // 131072 u32

    k1<<<1152, 256, 0, stream>>>(emb, Wqk, bqk, qb, kNb, Wv, WvTb, mask, mbp);
    kF<<<960, 256, 0, stream>>>(qb, kNb, scb, value, WvTb, bvv, vtb);
    kC<<<dim3(4, T_, B_), 256, 0, stream>>>(scb, mbp, vtb, out);
}